// Round 5
// baseline (398.117 us; speedup 1.0000x reference)
//
#include <hip/hip_runtime.h>
#include <hip/hip_bf16.h>
#include <hip/hip_fp16.h>

typedef _Float16 f16;
typedef _Float16 half8 __attribute__((ext_vector_type(8)));
typedef _Float16 half4 __attribute__((ext_vector_type(4)));
typedef float f32x4 __attribute__((ext_vector_type(4)));

// A&S 7.1.26 erf (|err| < 1.5e-7), ~15 VALU + 1 trans vs libm erff's ~40
__device__ __forceinline__ float gelu_f(float x) {
  const float z = fabsf(x) * 0.70710678118654752f;
  const float t = __builtin_amdgcn_rcpf(1.0f + 0.3275911f * z);
  const float poly = t * (0.254829592f + t * (-0.284496736f + t * (1.421413741f +
                     t * (-1.453152027f + t * 1.061405429f))));
  float er = 1.0f - poly * __expf(-z * z);
  er = __int_as_float(__float_as_int(er) | (__float_as_int(x) & 0x80000000));
  return 0.5f * x * (1.0f + er);
}

__device__ __forceinline__ void gll16(const void* g, void* l) {
  __builtin_amdgcn_global_load_lds((const __attribute__((address_space(1))) void*)g,
                                   (__attribute__((address_space(3))) void*)l,
                                   16, 0, 0);
}

// ---------------------------------------------------------------------------
// gemm_pan: D[M][4096-n] (+split) = act( W[M][KK] · Act_panel[n][KK]^T + bias )
// One 64-n panel per block. 512 thr / 8 waves; wave owns MW m-rows.
// W-frags read per-k-step from global (L2-resident). Act staged once in LDS:
//   STAGE 0: f16 source, K-inner rows, gll16 w/ source-chunk XOR swizzle
//   STAGE 1: f32 source [K-rows][n-cols], reg-staged transpose+cvt to f16
// XOR key (row&7) identical on stage and read (both-sides rule).
// OUTMODE: 0 f16 D[r][ldD]+col ; 1 f16 half4 transposed D[col][ldD]+r (lvT) ;
//          2 f32 D[r][ldD]+col ; 3 f32 split-slab part[slab][r][col]
// BIASMODE: 0 none ; 1 bias[r] ; 2 lv-remap bias[r + (r>=256)*256]
template<int M, int KK, int MW, int STAGE, int OUTMODE, int BIASMODE, bool GELU_ACT, bool KSPLIT>
__global__ __launch_bounds__(512, 4)
void gemm_pan(const f16* __restrict__ W, size_t sW, int ldW,
              const void* __restrict__ Act, size_t sA, int ldA,
              void* __restrict__ Dv, size_t sD, int ldD,
              const float* __restrict__ bias)
{
  constexpr int PN = 64;
  constexpr int NT = 4;
  constexpr int MT = MW / 16;
  constexpr int NKS = KK / 32;
  constexpr int ROWB = KK * 2;
  __shared__ __align__(16) char lds[PN * ROWB];

  const int t = threadIdx.x, l = t & 63, w = t >> 6;
  int b, koff, slab;
  if (KSPLIT) { b = blockIdx.y >> 3; koff = (blockIdx.y & 7) * KK; slab = blockIdx.y; }
  else        { b = blockIdx.y; koff = 0; slab = 0; }
  const int n0 = blockIdx.x * PN;
  const f16* Wb = W + (size_t)b * sW + koff;

  if (STAGE == 0) {
    const f16* Ab = (const f16*)Act + (size_t)b * sA + (size_t)n0 * ldA + koff;
    constexpr int SIT = PN * ROWB / 8192;
#pragma unroll
    for (int i = 0; i < SIT; ++i) {
      const int o = (i * 512 + t) * 16;
      const int row = o / ROWB;
      const int ch = ((o % ROWB) >> 4) ^ (row & 7);
      gll16(Ab + (size_t)row * ldA + ch * 8, lds + o);
    }
  } else {
    // Act f32 [KK rows][n]; produce LDS [64 n][KK] f16
    const float* Af = (const float*)Act + (size_t)b * sA + n0;
    const int nb = (l & 15) * 4;           // 4 consecutive n per lane
    const int ebase = (t >> 4) * 2;        // even K-row
#pragma unroll
    for (int ei = 0; ei < KK / 64; ++ei) {
      const int ea = ebase + ei * 64;
      float4 va = *(const float4*)(Af + (size_t)ea * ldA + nb);
      float4 vb = *(const float4*)(Af + (size_t)(ea + 1) * ldA + nb);
      const float* pa = (const float*)&va;
      const float* pb = (const float*)&vb;
#pragma unroll
      for (int j = 0; j < 4; ++j) {
        const int nloc = nb + j;
        const int pc = (ea >> 3) ^ (nloc & 7);
        f16 h0 = (f16)pa[j], h1 = (f16)pb[j];
        unsigned u = (unsigned)*(const unsigned short*)&h0 |
                     ((unsigned)*(const unsigned short*)&h1 << 16);
        *(unsigned*)(lds + nloc * ROWB + pc * 16 + (ea & 7) * 2) = u;
      }
    }
  }
  __syncthreads();

  f32x4 acc[MT][NT];
#pragma unroll
  for (int mt = 0; mt < MT; ++mt)
#pragma unroll
    for (int nt = 0; nt < NT; ++nt)
      acc[mt][nt] = (f32x4){0.f, 0.f, 0.f, 0.f};

#pragma unroll 2
  for (int ks = 0; ks < NKS; ++ks) {
    half8 af[MT], bf[NT];
#pragma unroll
    for (int mt = 0; mt < MT; ++mt) {
      const int row = w * MW + mt * 16 + (l & 15);
      af[mt] = *(const half8*)(Wb + (size_t)row * ldW + ks * 32 + (l >> 4) * 8);
    }
#pragma unroll
    for (int nt = 0; nt < NT; ++nt) {
      const int row = nt * 16 + (l & 15);
      const int ch = (ks * 4 + (l >> 4)) ^ (row & 7);
      bf[nt] = *(const half8*)(lds + row * ROWB + ch * 16);
    }
#pragma unroll
    for (int mt = 0; mt < MT; ++mt)
#pragma unroll
      for (int nt = 0; nt < NT; ++nt)
        acc[mt][nt] = __builtin_amdgcn_mfma_f32_16x16x32_f16(af[mt], bf[nt], acc[mt][nt], 0, 0, 0);
  }

#pragma unroll
  for (int mt = 0; mt < MT; ++mt) {
    const int rb = w * MW + mt * 16 + ((l >> 4) << 2);
#pragma unroll
    for (int nt = 0; nt < NT; ++nt) {
      const int col = n0 + nt * 16 + (l & 15);
      if (OUTMODE == 1) {
        half4 h;
#pragma unroll
        for (int j = 0; j < 4; ++j) {
          const int rr = rb + j;
          float v = acc[mt][nt][j];
          if (BIASMODE == 1) v += bias[rr];
          if (BIASMODE == 2) v += bias[rr + (rr >= 256 ? 256 : 0)];
          if (GELU_ACT) v = gelu_f(v);
          h[j] = (f16)v;
        }
        *(half4*)((f16*)Dv + (size_t)b * sD + (size_t)col * ldD + rb) = h;
      } else {
#pragma unroll
        for (int j = 0; j < 4; ++j) {
          const int rr = rb + j;
          float v = acc[mt][nt][j];
          if (BIASMODE == 1) v += bias[rr];
          if (BIASMODE == 2) v += bias[rr + (rr >= 256 ? 256 : 0)];
          if (GELU_ACT) v = gelu_f(v);
          if (OUTMODE == 0) ((f16*)Dv + (size_t)b * sD)[(size_t)rr * ldD + col] = (f16)v;
          if (OUTMODE == 2) ((float*)Dv + (size_t)b * sD)[(size_t)rr * ldD + col] = v;
          if (OUTMODE == 3) ((float*)Dv)[(size_t)slab * (size_t)(M * 256) + (size_t)rr * ldD + col] = v;
        }
      }
    }
  }
}

// ---------------- gemm_tn (r4, proven) — used only for the tiny Wxp GEMM
#define BM 128
#define BN 128
#define BK 32
template<int BIAS, bool GELU_ACT, bool OUT_F16, bool KSPLIT>
__global__ __launch_bounds__(256)
void gemm_tn(const f16* __restrict__ P, size_t sP, int ldP,
             const f16* __restrict__ Q, size_t sQ, int ldQ,
             void* __restrict__ Dv, size_t sD, int ldD,
             const float* __restrict__ bias, const float* __restrict__ bias2,
             int M, int N, int K, int nks)
{
  __shared__ __align__(16) char lds[32768];
  const int t = threadIdx.x;
  const int l = t & 63;
  const int wid = t >> 6;
  const int wr = wid >> 1;
  const int wc = wid & 1;
  const int z = blockIdx.z;
  const int b = z / nks;
  const int s = z - b * nks;
  const int kLen = K / nks;
  const int k0 = s * kLen;
  const int mBase = blockIdx.y * BM;
  const int nBase = blockIdx.x * BN;
  const f16* Pb = P + (size_t)b * sP;
  const f16* Qb = Q + (size_t)b * sQ;

  const f16* srcA[2];
  const f16* srcB[2];
  int dstOff[2];
#pragma unroll
  for (int c = 0; c < 2; ++c) {
    const int off = c * 4096 + wid * 1024 + l * 16;
    const int row = off >> 6;
    const int gch = ((off >> 4) & 3) ^ ((row >> 1) & 3);
    srcA[c] = Pb + (size_t)(mBase + row) * ldP + k0 + gch * 8;
    srcB[c] = Qb + (size_t)(nBase + row) * ldQ + k0 + gch * 8;
    dstOff[c] = c * 4096 + wid * 1024;
  }
  auto stage = [&](int bufi) {
#pragma unroll
    for (int c = 0; c < 2; ++c) {
      gll16(srcA[c], lds + bufi * 8192 + dstOff[c]);
      gll16(srcB[c], lds + 16384 + bufi * 8192 + dstOff[c]);
      srcA[c] += BK;
      srcB[c] += BK;
    }
  };
  f32x4 acc[4][4];
#pragma unroll
  for (int i = 0; i < 4; ++i)
#pragma unroll
    for (int j = 0; j < 4; ++j)
      acc[i][j] = (f32x4){0.f, 0.f, 0.f, 0.f};

  const int nk = kLen / BK;
  stage(0);
  int buf = 0;
  for (int kt = 0; kt < nk; ++kt) {
    if (kt + 1 < nk) {
      stage(buf ^ 1);
      asm volatile("s_waitcnt vmcnt(4)" ::: "memory");
    } else {
      asm volatile("s_waitcnt vmcnt(0)" ::: "memory");
    }
    asm volatile("s_barrier" ::: "memory");
    half8 af[4], bf[4];
#pragma unroll
    for (int mi = 0; mi < 4; ++mi) {
      const int row = wr * 64 + mi * 16 + (l & 15);
      const int phys = row * 64 + ((((l >> 4) ^ (row >> 1)) & 3) << 4);
      af[mi] = *(const half8*)(lds + buf * 8192 + phys);
    }
#pragma unroll
    for (int ni = 0; ni < 4; ++ni) {
      const int row = wc * 64 + ni * 16 + (l & 15);
      const int phys = row * 64 + ((((l >> 4) ^ (row >> 1)) & 3) << 4);
      bf[ni] = *(const half8*)(lds + 16384 + buf * 8192 + phys);
    }
#pragma unroll
    for (int mi = 0; mi < 4; ++mi)
#pragma unroll
      for (int ni = 0; ni < 4; ++ni)
        acc[mi][ni] = __builtin_amdgcn_mfma_f32_16x16x32_f16(af[mi], bf[ni], acc[mi][ni], 0, 0, 0);
    asm volatile("s_barrier" ::: "memory");
    buf ^= 1;
  }

  float* Dsplit = nullptr; f16* D16 = nullptr; float* D32 = nullptr;
  if (KSPLIT)       Dsplit = (float*)Dv + (size_t)z * (size_t)(M * N);
  else if (OUT_F16) D16    = (f16*)Dv + (size_t)b * sD;
  else              D32    = (float*)Dv + (size_t)b * sD;
#pragma unroll
  for (int mi = 0; mi < 4; ++mi) {
    const int rb = mBase + wr * 64 + mi * 16 + ((l >> 4) << 2);
#pragma unroll
    for (int ni = 0; ni < 4; ++ni) {
      const int col = nBase + wc * 64 + ni * 16 + (l & 15);
#pragma unroll
      for (int j = 0; j < 4; ++j) {
        float v = acc[mi][ni][j];
        const int rr = rb + j;
        if (BIAS == 1) v += bias[rr];
        if (BIAS == 2) v += bias[col];
        if (GELU_ACT) v = gelu_f(v);
        if (KSPLIT)       Dsplit[(size_t)rr * ldD + col] = v;
        else if (OUT_F16) D16[(size_t)rr * ldD + col] = (f16)v;
        else              D32[(size_t)rr * ldD + col] = v;
      }
    }
  }
}

// ---------------- small kernels
__global__ __launch_bounds__(256)
void cvtf16(const float* __restrict__ in, f16* __restrict__ outp, int n8) {
  int i = blockIdx.x * 256 + threadIdx.x;
  if (i < n8) {
    float4 a = ((const float4*)in)[2 * i];
    float4 c = ((const float4*)in)[2 * i + 1];
    half8 h = {(f16)a.x, (f16)a.y, (f16)a.z, (f16)a.w,
               (f16)c.x, (f16)c.y, (f16)c.z, (f16)c.w};
    ((half8*)outp)[i] = h;
  }
}

__global__ __launch_bounds__(256)
void wsplit(const float* __restrict__ wp, f16* __restrict__ Wx, f16* __restrict__ Wcat) {
  const int o = blockIdx.x, c = threadIdx.x;
  const f16 lf = (f16)wp[o * 512 + c];
  Wx[o * 256 + c] = (f16)wp[o * 512 + 256 + c];
#pragma unroll
  for (int b = 0; b < 16; ++b) Wcat[(size_t)b * 131072 + o * 512 + c] = lf;
}

// sum 8 split slabs of qk, row-softmax over d, write transposed pT[d][c] f16
__global__ __launch_bounds__(256)
void softmaxT8(const float* __restrict__ part, f16* __restrict__ pT) {
  __shared__ f16 sm[4][256];
  const int wid = threadIdx.x >> 6, l = threadIdx.x & 63;
  const int b = blockIdx.y;
  const int c = blockIdx.x * 4 + wid;
  float v[4] = {0.f, 0.f, 0.f, 0.f};
  for (int s = 0; s < 8; ++s) {
    const float* row = part + ((size_t)(b * 8 + s) * 65536) + (size_t)c * 256;
#pragma unroll
    for (int j = 0; j < 4; ++j) v[j] += row[l + 64 * j];
  }
  float m = fmaxf(fmaxf(v[0], v[1]), fmaxf(v[2], v[3]));
#pragma unroll
  for (int off = 32; off; off >>= 1) m = fmaxf(m, __shfl_xor(m, off));
  float e[4], sum = 0.f;
#pragma unroll
  for (int j = 0; j < 4; ++j) { e[j] = expf(v[j] - m); sum += e[j]; }
#pragma unroll
  for (int off = 32; off; off >>= 1) sum += __shfl_xor(sum, off);
  const float inv = 1.0f / sum;
#pragma unroll
  for (int j = 0; j < 4; ++j) sm[wid][l + 64 * j] = (f16)(e[j] * inv);
  __syncthreads();
  const int d = threadIdx.x;
  half4 h = {sm[0][d], sm[1][d], sm[2][d], sm[3][d]};
  *(half4*)(pT + ((size_t)b * 256 + d) * 256 + blockIdx.x * 4) = h;
}

extern "C" void kernel_launch(void* const* d_in, const int* in_sizes, int n_in,
                              void* d_out, int out_size, void* d_ws, size_t ws_size,
                              hipStream_t stream) {
  const float* x      = (const float*)d_in[0];
  const float* qin    = (const float*)d_in[1];
  const float* w_kvl  = (const float*)d_in[2];
  const float* b_kvl  = (const float*)d_in[3];
  const float* w_q    = (const float*)d_in[4];
  const float* b_q    = (const float*)d_in[5];
  const float* w_proj = (const float*)d_in[6];
  const float* b_proj = (const float*)d_in[7];
  float* out = (float*)d_out;
  char* ws = (char*)d_ws;

  if (ws_size < 210000000) return;

  f16*   kH    = (f16*)(ws + 0);            // [16][256][4096]
  f16*   lvT   = (f16*)(ws + 33554432);     // [16][4096][512]
  f16*   qH    = (f16*)(ws + 100663296);    // [16][256][4096]
  float* part  = (float*)(ws + 134217728);  // [128][256][256] f32 qk split slabs
  f16*   pT    = (f16*)(ws + 167772160);    // [16][256][256]
  f16*   Wcat  = (f16*)(ws + 169869312);    // [16][256][512]
  f16*   wkK   = (f16*)(ws + 174063616);    // [256][256]
  f16*   wk_lv = (f16*)(ws + 174194688);    // [512][256]
  f16*   wq16  = (f16*)(ws + 174456832);    // [256][256]
  f16*   Wx16  = (f16*)(ws + 174587904);    // [256][256]

  const size_t sAct = 1048576;
  dim3 blk(256), blk512(512);

  cvtf16<<<dim3(32), blk, 0, stream>>>(w_kvl + 65536, wkK, 8192);             // k rows
  cvtf16<<<dim3(32), blk, 0, stream>>>(w_kvl, wk_lv, 8192);                   // lfeat rows
  cvtf16<<<dim3(32), blk, 0, stream>>>(w_kvl + 131072, wk_lv + 65536, 8192);  // v rows
  cvtf16<<<dim3(32), blk, 0, stream>>>(w_q, wq16, 8192);
  wsplit<<<dim3(256), blk, 0, stream>>>(w_proj, Wx16, Wcat);

  // kH[d][n] = gelu(wkK·x + b_kvl[256:512])   (x read as f32, transposed in LDS)
  hipLaunchKernelGGL((gemm_pan<256, 256, 32, 1, 0, 1, true, false>), dim3(64, 16), blk512, 0, stream,
      wkK, (size_t)0, 256, (const void*)x, sAct, 4096,
      (void*)kH, sAct, 4096, b_kvl + 256);
  // lvT[n][512] = gelu([wk0;wk2]·x + b) stored transposed
  hipLaunchKernelGGL((gemm_pan<512, 256, 64, 1, 1, 2, true, false>), dim3(64, 16), blk512, 0, stream,
      wk_lv, (size_t)0, 256, (const void*)x, sAct, 4096,
      (void*)lvT, (size_t)2097152, 512, b_kvl);
  // qH[c][n] = wq·qin + b_q   (qin read as f32)
  hipLaunchKernelGGL((gemm_pan<256, 256, 32, 1, 0, 1, false, false>), dim3(64, 16), blk512, 0, stream,
      wq16, (size_t)0, 256, (const void*)qin, sAct, 4096,
      (void*)qH, sAct, 4096, b_q);
  // qk split-8: part[b*8+s][c][d] = qH[c][nwin]·kH[d][nwin]^T
  hipLaunchKernelGGL((gemm_pan<256, 512, 32, 0, 3, 0, false, true>), dim3(4, 128), blk512, 0, stream,
      qH, sAct, 4096, (const void*)kH, sAct, 4096,
      (void*)part, (size_t)0, 256, (const float*)nullptr);
  // softmax rows over d (8-slab reduce) -> pT[d][c]
  softmaxT8<<<dim3(64, 16), blk, 0, stream>>>(part, pT);
  // Wxp[o][d] = Wx·p -> Wcat[:, 256:512]
  hipLaunchKernelGGL((gemm_tn<0, false, true, false>), dim3(2, 2, 16), blk, 0, stream,
      Wx16, (size_t)0, 256, pT, (size_t)65536, 256,
      (void*)(Wcat + 256), (size_t)131072, 512, (const float*)nullptr, (const float*)nullptr, 256, 256, 256, 1);
  // out[o][n] = gelu(Wcat_b·lvT^T + b_proj) f32
  hipLaunchKernelGGL((gemm_pan<256, 512, 32, 0, 2, 1, true, false>), dim3(64, 16), blk512, 0, stream,
      Wcat, (size_t)131072, 512, (const void*)lvT, (size_t)2097152, 512,
      (void*)out, sAct, 4096, b_proj);
}